// Round 1
// baseline (405.028 us; speedup 1.0000x reference)
//
#include <hip/hip_runtime.h>
#include <math.h>

#define HH    256
#define WWID  256
#define WSZ   8
#define SSZ   4
#define NHEAD 3
#define CCH   96
#define DFF   384

#define XW_LD 104   // bf16 elems; 208 B rows
#define QK_LD 200   // 400 B rows (Q 0..95 -> O; K 96..191); reused as H[64][200]
#define VT_LD 72    // 144 B rows
#define H_LD  200

using bf16x8 = __attribute__((ext_vector_type(8))) short;
using f32x4  = __attribute__((ext_vector_type(4))) float;
using int2v  = __attribute__((ext_vector_type(2))) int;

#define LOG2E 1.44269504088896f

__device__ __forceinline__ unsigned short f2bf(float f) {   // prep only
    unsigned u = __float_as_uint(f);
    return (unsigned short)((u + 0x7FFFu + ((u >> 16) & 1u)) >> 16);
}
__device__ __forceinline__ float bf2f(unsigned short s) {
    return __uint_as_float(((unsigned)s) << 16);
}
// HW packed f32->bf16 (RNE): 1 VOP3 per pair. lo -> bits[15:0], hi -> bits[31:16].
__device__ __forceinline__ unsigned cvtpk(float lo, float hi) {
    unsigned r;
    asm("v_cvt_pk_bf16_f32 %0, %1, %2" : "=v"(r) : "v"(lo), "v"(hi));
    return r;
}
__device__ __forceinline__ float lo2f(unsigned u) { return __uint_as_float(u << 16); }
__device__ __forceinline__ float hi2f(unsigned u) { return __uint_as_float(u & 0xFFFF0000u); }

__device__ __forceinline__ float gelu_t(float t) {
    float t2 = t * t;
    float u  = t * (0.7978845608028654f + 0.03567740814183f * t2);
    float e  = exp2f(u * 2.885390081777927f);
    float rc = __builtin_amdgcn_rcpf(e + 1.f);
    return t - t * rc;
}

// ---------------- workspace: bf16 packs + combined bias/mask table ----------------
#define WQ_OFF  0
#define WP_OFF  27648
#define W1_OFF  36864
#define W2_OFF  73728
#define CT_OFF  110592

// frag(tile t, kstep s, lane l, j) = W[t*16 + l%16][s*32 + (l/16)*8 + j]
__global__ void __launch_bounds__(256)
prep(const float* __restrict__ qkvw, const float* __restrict__ pw,
     const float* __restrict__ w1, const float* __restrict__ w2,
     const float* __restrict__ rpb, unsigned short* __restrict__ wsq)
{
    int e = blockIdx.x * 256 + threadIdx.x;
    if (e < 110592) {
        const float* W; int Kd, nk, i = e;
        if (i < 27648)      { W = qkvw; Kd = 96;  nk = 3;  }
        else if (i < 36864) { W = pw;   Kd = 96;  nk = 3;  i -= 27648; }
        else if (i < 73728) { W = w1;   Kd = 96;  nk = 3;  i -= 36864; }
        else                { W = w2;   Kd = 384; nk = 12; i -= 73728; }
        int j = i & 7, fe = i >> 3;
        int lane = fe & 63, q = fe >> 6;
        int ks = q % nk, t = q / nk;
        int row = t * 16 + (lane & 15);
        int col = ks * 32 + (lane >> 4) * 8 + j;
        wsq[e] = f2bf(W[(size_t)row * Kd + col]);
    } else if (e < 159744) {
        int i = e - 110592;
        int cls = i / 12288;
        int rem = i - cls * 12288;
        int h = rem >> 12, n = (rem >> 6) & 63, m = rem & 63;
        int rel = ((n >> 3) - (m >> 3) + 7) * 15 + ((n & 7) - (m & 7) + 7);
        float bias = rpb[rel * NHEAD + h];
        int ci = cls >> 1, cj = cls & 1;
        int rn = (ci ? ((n >> 3) < 4 ? 1 : 2) : 0) * 3 + (cj ? ((n & 7) < 4 ? 1 : 2) : 0);
        int rm = (ci ? ((m >> 3) < 4 ? 1 : 2) : 0) * 3 + (cj ? ((m & 7) < 4 ? 1 : 2) : 0);
        float mask = (rn != rm) ? -100.f : 0.f;
        wsq[CT_OFF + i] = f2bf((bias + mask) * LOG2E);
    }
}

// ---------------- Fused block. LDS 39424 B -> 4 blocks/CU. N-split weight GEMMs.
// P-transpose done fully in registers (permlane32_swap + ds_swizzle xor16), sP eliminated.
__global__ void __launch_bounds__(256, 4)
fused(const float* __restrict__ x,
      const float* __restrict__ n1w, const float* __restrict__ n1b,
      const float* __restrict__ qkvb, const float* __restrict__ pb,
      const float* __restrict__ n2w, const float* __restrict__ n2b,
      const float* __restrict__ b1, const float* __restrict__ b2,
      const unsigned short* __restrict__ wsq,
      float* __restrict__ y)
{
    __shared__ unsigned short SM[19712];           // 39424 B
    unsigned short* sR1 = SM;                      // XW -> VT -> proj-out -> XN -> mlp-out
    unsigned short* sQK = SM + 6912;               // QK[64][200] -> H[64][200]

    const int bwin = blockIdx.x;
    const int b  = bwin >> 10;
    const int wi = (bwin >> 5) & 31;
    const int wj = bwin & 31;
    const int tid = threadIdx.x;
    const int lane = tid & 63;
    const int wave = tid >> 6;
    const int l15 = lane & 15;
    const int l16 = lane >> 4;
    const int nb = wave * 16;
    const int sub = lane & 3;

    // token-major identity: this lane covers token tm = nb + (lane>>2), channels sub*24..+23
    const int tm  = nb + (lane >> 2);
    const int gh1 = ((wi << 3) + (tm >> 3) + SSZ) & (HH - 1);
    const int gw1 = ((wj << 3) + (tm & 7) + SSZ) & (WWID - 1);
    const size_t rowtm = ((size_t)b * (HH * WWID) + (size_t)gh1 * WWID + gw1) * CCH;

    // ---- Phase 1: load x (kept in regs), LN1, XW -> LDS ----
    f32x4 xv[6];
    {
        const float* xr = x + rowtm + sub * 24;
#pragma unroll
        for (int q = 0; q < 6; ++q) xv[q] = *(const f32x4*)(xr + 4 * q);
        float s1 = 0.f, s2 = 0.f;
#pragma unroll
        for (int q = 0; q < 6; ++q)
#pragma unroll
            for (int r = 0; r < 4; ++r) { s1 += xv[q][r]; s2 = fmaf(xv[q][r], xv[q][r], s2); }
        s1 += __shfl_xor(s1, 1);  s2 += __shfl_xor(s2, 1);
        s1 += __shfl_xor(s1, 2);  s2 += __shfl_xor(s2, 2);
        const float mean = s1 * (1.f / CCH);
        const float rstd = rsqrtf(s2 * (1.f / CCH) - mean * mean + 1e-5f);
        unsigned o[12];
#pragma unroll
        for (int q = 0; q < 6; ++q) {
            const f32x4 wv = *(const f32x4*)&n1w[sub * 24 + 4 * q];
            const f32x4 bv = *(const f32x4*)&n1b[sub * 24 + 4 * q];
            float a0 = (xv[q][0] - mean) * rstd * wv[0] + bv[0];
            float a1 = (xv[q][1] - mean) * rstd * wv[1] + bv[1];
            float a2 = (xv[q][2] - mean) * rstd * wv[2] + bv[2];
            float a3 = (xv[q][3] - mean) * rstd * wv[3] + bv[3];
            o[2 * q] = cvtpk(a0, a1); o[2 * q + 1] = cvtpk(a2, a3);
        }
        unsigned* dst = (unsigned*)&sR1[tm * XW_LD + sub * 24];
#pragma unroll
        for (int q = 0; q < 3; ++q) {
            uint4 u; u.x = o[4 * q]; u.y = o[4 * q + 1]; u.z = o[4 * q + 2]; u.w = o[4 * q + 3];
            *(uint4*)(dst + 4 * q) = u;
        }
    }
    __syncthreads();   // B1: XW complete (all rows)

    // A-frags for ALL 4 row-tiles (N-split needs full M in regs)
    bf16x8 afr[4][3];
#pragma unroll
    for (int mt = 0; mt < 4; ++mt)
#pragma unroll
        for (int ks = 0; ks < 3; ++ks)
            afr[mt][ks] = *(const bf16x8*)&sR1[(mt * 16 + l15) * XW_LD + ks * 32 + l16 * 8];
    __syncthreads();   // B1b: XW fully read; sR1 becomes VT

    // ---- Phase 2: QKV N-split (each weight tile loaded by ONE wave, feeds 4 MFMAs) ----
    {
        const float qscale = 0.17677669529663689f * LOG2E;
        for (int nt = wave; nt < 18; nt += 4) {
            f32x4 acc[4] = {{0,0,0,0},{0,0,0,0},{0,0,0,0},{0,0,0,0}};
#pragma unroll
            for (int ks = 0; ks < 3; ++ks) {
                const bf16x8 wf = *(const bf16x8*)(wsq + ((size_t)(nt * 3 + ks) * 64 + lane) * 8);
#pragma unroll
                for (int mt = 0; mt < 4; ++mt)
                    acc[mt] = __builtin_amdgcn_mfma_f32_16x16x32_bf16(wf, afr[mt][ks], acc[mt], 0, 0, 0);
            }
            const f32x4 bias = *(const f32x4*)&qkvb[nt * 16 + 4 * l16];
            if (nt < 6) {
#pragma unroll
                for (int mt = 0; mt < 4; ++mt) {
                    uint2 u;
                    u.x = cvtpk((acc[mt][0] + bias[0]) * qscale, (acc[mt][1] + bias[1]) * qscale);
                    u.y = cvtpk((acc[mt][2] + bias[2]) * qscale, (acc[mt][3] + bias[3]) * qscale);
                    *(uint2*)&sQK[(mt * 16 + l15) * QK_LD + nt * 16 + 4 * l16] = u;
                }
            } else if (nt < 12) {
#pragma unroll
                for (int mt = 0; mt < 4; ++mt) {
                    uint2 u;
                    u.x = cvtpk(acc[mt][0] + bias[0], acc[mt][1] + bias[1]);
                    u.y = cvtpk(acc[mt][2] + bias[2], acc[mt][3] + bias[3]);
                    *(uint2*)&sQK[(mt * 16 + l15) * QK_LD + nt * 16 + 4 * l16] = u;
                }
            } else {
                const int ch = nt * 16 - 192 + 4 * l16;
#pragma unroll
                for (int mt = 0; mt < 4; ++mt) {
                    const unsigned v01 = cvtpk(acc[mt][0] + bias[0], acc[mt][1] + bias[1]);
                    const unsigned v23 = cvtpk(acc[mt][2] + bias[2], acc[mt][3] + bias[3]);
                    sR1[(ch + 0) * VT_LD + mt * 16 + l15] = (unsigned short)v01;
                    sR1[(ch + 1) * VT_LD + mt * 16 + l15] = (unsigned short)(v01 >> 16);
                    sR1[(ch + 2) * VT_LD + mt * 16 + l15] = (unsigned short)v23;
                    sR1[(ch + 3) * VT_LD + mt * 16 + l15] = (unsigned short)(v23 >> 16);
                }
            }
        }
    }
    __syncthreads();   // B2: Q, K, V visible to all waves

    // ---- Phase 3: attention, M-split, in-register P transpose (no sP) ----
    // C-layout after mfma(kf,qf): lane(g=l16,t=l15) holds P[n=t][m = mt*16 + g*4 + r].
    // B-frag needs lane(g,t): P[n=t][m = ks*32 + g*8 + j], j=0..7.
    // With A_q=u[2ks][q], B_q=u[2ks+1][q]: (X,Y)=permlane32_swap(A,B) gives
    //   X = {A.lo | B.lo}, Y = {A.hi | B.hi}; S* = xor16-swizzle.
    // even g: pf = {X0,X1,SX0,SX1}; odd g: pf = {SY0,SY1,Y0,Y1}.
    {
        const int cls = ((wi == 31) ? 2 : 0) + ((wj == 31) ? 1 : 0);
        const unsigned short* ctb = wsq + CT_OFF + cls * 12288;
        const bool godd = (l16 & 1) != 0;
#pragma unroll 1
        for (int h = 0; h < NHEAD; ++h) {
            const bf16x8 qf = *(const bf16x8*)&sQK[(nb + l15) * QK_LD + h * 32 + l16 * 8];
            f32x4 s[4];
#pragma unroll
            for (int mt = 0; mt < 4; ++mt) {
                const bf16x8 kf = *(const bf16x8*)&sQK[(mt * 16 + l15) * QK_LD + CCH + h * 32 + l16 * 8];
                f32x4 z = {0, 0, 0, 0};
                s[mt] = __builtin_amdgcn_mfma_f32_16x16x32_bf16(kf, qf, z, 0, 0, 0);
            }
            const unsigned short* cth = ctb + h * 4096 + (nb + l15) * 64;
            unsigned u[4][2];
            float rsum = 0.f;
#pragma unroll
            for (int mt = 0; mt < 4; ++mt) {
                const ushort4 c4 = *(const ushort4*)&cth[mt * 16 + 4 * l16];
                const float pv0 = exp2f(s[mt][0] + bf2f(c4.x));
                const float pv1 = exp2f(s[mt][1] + bf2f(c4.y));
                const float pv2 = exp2f(s[mt][2] + bf2f(c4.z));
                const float pv3 = exp2f(s[mt][3] + bf2f(c4.w));
                rsum += pv0 + pv1 + pv2 + pv3;
                u[mt][0] = cvtpk(pv0, pv1);
                u[mt][1] = cvtpk(pv2, pv3);
            }
            rsum += __shfl_xor(rsum, 16);
            rsum += __shfl_xor(rsum, 32);
            const float rinv = __builtin_amdgcn_rcpf(rsum);
            f32x4 o[2] = {{0,0,0,0},{0,0,0,0}};
#pragma unroll
            for (int ks = 0; ks < 2; ++ks) {
                const int2v r0 = __builtin_amdgcn_permlane32_swap(
                    (int)u[2 * ks][0], (int)u[2 * ks + 1][0], false, false);
                const int2v r1 = __builtin_amdgcn_permlane32_swap(
                    (int)u[2 * ks][1], (int)u[2 * ks + 1][1], false, false);
                const unsigned X0 = (unsigned)r0[0], Y0 = (unsigned)r0[1];
                const unsigned X1 = (unsigned)r1[0], Y1 = (unsigned)r1[1];
                const unsigned SX0 = (unsigned)__builtin_amdgcn_ds_swizzle((int)X0, 0x401F);
                const unsigned SX1 = (unsigned)__builtin_amdgcn_ds_swizzle((int)X1, 0x401F);
                const unsigned SY0 = (unsigned)__builtin_amdgcn_ds_swizzle((int)Y0, 0x401F);
                const unsigned SY1 = (unsigned)__builtin_amdgcn_ds_swizzle((int)Y1, 0x401F);
                union { unsigned w[4]; bf16x8 v; } pk;
                pk.w[0] = godd ? SY0 : X0;
                pk.w[1] = godd ? SY1 : X1;
                pk.w[2] = godd ? Y0 : SX0;
                pk.w[3] = godd ? Y1 : SX1;
#pragma unroll
                for (int dt = 0; dt < 2; ++dt) {
                    const bf16x8 vf = *(const bf16x8*)&sR1[(h * 32 + dt * 16 + l15) * VT_LD + ks * 32 + l16 * 8];
                    o[dt] = __builtin_amdgcn_mfma_f32_16x16x32_bf16(vf, pk.v, o[dt], 0, 0, 0);
                }
            }
#pragma unroll
            for (int dt = 0; dt < 2; ++dt) {
                uint2 uo;
                uo.x = cvtpk(o[dt][0] * rinv, o[dt][1] * rinv);
                uo.y = cvtpk(o[dt][2] * rinv, o[dt][3] * rinv);
                *(uint2*)&sQK[(nb + l15) * QK_LD + h * 32 + dt * 16 + 4 * l16] = uo;
            }
        }
    }
    __syncthreads();   // B3: O complete (all rows); VT fully consumed

    // ---- Phase 4: proj N-split -> proj-out chan-major (all rows) ----
    {
        bf16x8 ofr[4][3];
#pragma unroll
        for (int mt = 0; mt < 4; ++mt)
#pragma unroll
            for (int ks = 0; ks < 3; ++ks)
                ofr[mt][ks] = *(const bf16x8*)&sQK[(mt * 16 + l15) * QK_LD + ks * 32 + l16 * 8];
        const unsigned short* wp = wsq + WP_OFF;
        for (int ct = wave; ct < 6; ct += 4) {
            f32x4 acc[4] = {{0,0,0,0},{0,0,0,0},{0,0,0,0},{0,0,0,0}};
#pragma unroll
            for (int ks = 0; ks < 3; ++ks) {
                const bf16x8 wf = *(const bf16x8*)(wp + ((size_t)(ct * 3 + ks) * 64 + lane) * 8);
#pragma unroll
                for (int mt = 0; mt < 4; ++mt)
                    acc[mt] = __builtin_amdgcn_mfma_f32_16x16x32_bf16(wf, ofr[mt][ks], acc[mt], 0, 0, 0);
            }
            const f32x4 pbv = *(const f32x4*)&pb[ct * 16 + 4 * l16];
#pragma unroll
            for (int mt = 0; mt < 4; ++mt) {
                uint2 u;
                u.x = cvtpk(acc[mt][0] + pbv[0], acc[mt][1] + pbv[1]);
                u.y = cvtpk(acc[mt][2] + pbv[2], acc[mt][3] + pbv[3]);
                *(uint2*)&sR1[(mt * 16 + l15) * XW_LD + ct * 16 + 4 * l16] = u;
            }
        }
    }
    __syncthreads();   // B4: proj-out complete

    // ---- Phase 5: residual + LN2 (token-major regs); XN -> LDS (own rows) ----
    float y1tm[6][4];
    {
        const unsigned* src = (const unsigned*)&sR1[tm * XW_LD + sub * 24];
#pragma unroll
        for (int q3 = 0; q3 < 3; ++q3) {
            const uint4 u = *(const uint4*)(src + 4 * q3);
            y1tm[2 * q3][0]     = xv[2 * q3][0] + lo2f(u.x);
            y1tm[2 * q3][1]     = xv[2 * q3][1] + hi2f(u.x);
            y1tm[2 * q3][2]     = xv[2 * q3][2] + lo2f(u.y);
            y1tm[2 * q3][3]     = xv[2 * q3][3] + hi2f(u.y);
            y1tm[2 * q3 + 1][0] = xv[2 * q3 + 1][0] + lo2f(u.z);
            y1tm[2 * q3 + 1][1] = xv[2 * q3 + 1][1] + hi2f(u.z);
            y1tm[2 * q3 + 1][2] = xv[2 * q3 + 1][2] + lo2f(u.w);
            y1tm[2 * q3 + 1][3] = xv[2 * q3 + 1][3] + hi2f(u.w);
        }
        float s1 = 0.f, s2 = 0.f;
#pragma unroll
        for (int q = 0; q < 6; ++q)
#pragma unroll
            for (int r = 0; r < 4; ++r) { s1 += y1tm[q][r]; s2 = fmaf(y1tm[q][r], y1tm[q][r], s2); }
        s1 += __shfl_xor(s1, 1);  s2 += __shfl_xor(s2, 1);
        s1 += __shfl_xor(s1, 2);  s2 += __shfl_xor(s2, 2);
        const float mean = s1 * (1.f / CCH);
        const float rstd = rsqrtf(s2 * (1.f / CCH) - mean * mean + 1e-5f);
        unsigned o[12];
#pragma unroll
        for (int q = 0; q < 6; ++q) {
            const f32x4 wv = *(const f32x4*)&n2w[sub * 24 + 4 * q];
            const f32x4 bv = *(const f32x4*)&n2b[sub * 24 + 4 * q];
            float a0 = (y1tm[q][0] - mean) * rstd * wv[0] + bv[0];
            float a1 = (y1tm[q][1] - mean) * rstd * wv[1] + bv[1];
            float a2 = (y1tm[q][2] - mean) * rstd * wv[2] + bv[2];
            float a3 = (y1tm[q][3] - mean) * rstd * wv[3] + bv[3];
            o[2 * q] = cvtpk(a0, a1); o[2 * q + 1] = cvtpk(a2, a3);
        }
        unsigned* dst = (unsigned*)&sR1[tm * XW_LD + sub * 24];
#pragma unroll
        for (int q = 0; q < 3; ++q) {
            uint4 u; u.x = o[4 * q]; u.y = o[4 * q + 1]; u.z = o[4 * q + 2]; u.w = o[4 * q + 3];
            *(uint4*)(dst + 4 * q) = u;
        }
    }
    __syncthreads();   // B5: XN complete (all rows)

    bf16x8 xfr[4][3];
#pragma unroll
    for (int mt = 0; mt < 4; ++mt)
#pragma unroll
        for (int ks = 0; ks < 3; ++ks)
            xfr[mt][ks] = *(const bf16x8*)&sR1[(mt * 16 + l15) * XW_LD + ks * 32 + l16 * 8];

    // ---- Phase 6: MLP N-split, H in halves, persistent acc2[cti][mt] ----
    f32x4 acc2[2][4];
#pragma unroll
    for (int ci = 0; ci < 2; ++ci)
#pragma unroll
        for (int mt = 0; mt < 4; ++mt) acc2[ci][mt] = (f32x4){0, 0, 0, 0};
    const unsigned short* w2p = wsq + W2_OFF;
#pragma unroll 1
    for (int half = 0; half < 2; ++half) {
        const unsigned short* w1p = wsq + W1_OFF + (size_t)half * 12 * 3 * 64 * 8;
        for (int nt = wave; nt < 12; nt += 4) {
            f32x4 acc[4] = {{0,0,0,0},{0,0,0,0},{0,0,0,0},{0,0,0,0}};
#pragma unroll
            for (int ks = 0; ks < 3; ++ks) {
                const bf16x8 wf = *(const bf16x8*)(w1p + ((size_t)(nt * 3 + ks) * 64 + lane) * 8);
#pragma unroll
                for (int mt = 0; mt < 4; ++mt)
                    acc[mt] = __builtin_amdgcn_mfma_f32_16x16x32_bf16(wf, xfr[mt][ks], acc[mt], 0, 0, 0);
            }
            const f32x4 b1v = *(const f32x4*)&b1[(half * 12 + nt) * 16 + 4 * l16];
#pragma unroll
            for (int mt = 0; mt < 4; ++mt) {
                uint2 u;
                u.x = cvtpk(gelu_t(acc[mt][0] + b1v[0]), gelu_t(acc[mt][1] + b1v[1]));
                u.y = cvtpk(gelu_t(acc[mt][2] + b1v[2]), gelu_t(acc[mt][3] + b1v[3]));
                *(uint2*)&sQK[(mt * 16 + l15) * H_LD + nt * 16 + 4 * l16] = u;
            }
        }
        __syncthreads();   // H(half) complete
#pragma unroll
        for (int k6 = 0; k6 < 6; ++k6) {
            bf16x8 hfr[4];
#pragma unroll
            for (int mt = 0; mt < 4; ++mt)
                hfr[mt] = *(const bf16x8*)&sQK[(mt * 16 + l15) * H_LD + k6 * 32 + l16 * 8];
#pragma unroll
            for (int ci = 0; ci < 2; ++ci) {
                const int ct = wave + 4 * ci;
                if (ct < 6) {
                    const bf16x8 wf = *(const bf16x8*)(w2p + ((size_t)(ct * 12 + half * 6 + k6) * 64 + lane) * 8);
#pragma unroll
                    for (int mt = 0; mt < 4; ++mt)
                        acc2[ci][mt] = __builtin_amdgcn_mfma_f32_16x16x32_bf16(wf, hfr[mt], acc2[ci][mt], 0, 0, 0);
                }
            }
        }
        if (half == 0) __syncthreads();   // H consumed before overwrite
    }

    // ---- Final: mlp-out chan-major (all rows) -> B8 -> token-major +y1, coalesced store ----
    {
#pragma unroll
        for (int ci = 0; ci < 2; ++ci) {
            const int ct = wave + 4 * ci;
            if (ct < 6) {
                const f32x4 b2v = *(const f32x4*)&b2[ct * 16 + 4 * l16];
#pragma unroll
                for (int mt = 0; mt < 4; ++mt) {
                    uint2 u;
                    u.x = cvtpk(acc2[ci][mt][0] + b2v[0], acc2[ci][mt][1] + b2v[1]);
                    u.y = cvtpk(acc2[ci][mt][2] + b2v[2], acc2[ci][mt][3] + b2v[3]);
                    *(uint2*)&sR1[(mt * 16 + l15) * XW_LD + ct * 16 + 4 * l16] = u;
                }
            }
        }
    }
    __syncthreads();   // B8: mlp-out complete
    {
        const unsigned* src = (const unsigned*)&sR1[tm * XW_LD + sub * 24];
        float* yr = y + rowtm + sub * 24;
#pragma unroll
        for (int q3 = 0; q3 < 3; ++q3) {
            const uint4 u = *(const uint4*)(src + 4 * q3);
            f32x4 o0, o1;
            o0[0] = y1tm[2 * q3][0] + lo2f(u.x);
            o0[1] = y1tm[2 * q3][1] + hi2f(u.x);
            o0[2] = y1tm[2 * q3][2] + lo2f(u.y);
            o0[3] = y1tm[2 * q3][3] + hi2f(u.y);
            o1[0] = y1tm[2 * q3 + 1][0] + lo2f(u.z);
            o1[1] = y1tm[2 * q3 + 1][1] + hi2f(u.z);
            o1[2] = y1tm[2 * q3 + 1][2] + lo2f(u.w);
            o1[3] = y1tm[2 * q3 + 1][3] + hi2f(u.w);
            *(f32x4*)(yr + 8 * q3)     = o0;
            *(f32x4*)(yr + 8 * q3 + 4) = o1;
        }
    }
}

extern "C" void kernel_launch(void* const* d_in, const int* in_sizes, int n_in,
                              void* d_out, int out_size, void* d_ws, size_t ws_size,
                              hipStream_t stream)
{
    const float* x    = (const float*)d_in[0];
    const float* n1w  = (const float*)d_in[1];
    const float* n1b  = (const float*)d_in[2];
    const float* qkvw = (const float*)d_in[3];
    const float* qkvb = (const float*)d_in[4];
    const float* rpb  = (const float*)d_in[5];
    const float* pw   = (const float*)d_in[6];
    const float* pb   = (const float*)d_in[7];
    const float* n2w  = (const float*)d_in[8];
    const float* n2b  = (const float*)d_in[9];
    const float* w1   = (const float*)d_in[10];
    const float* b1   = (const float*)d_in[11];
    const float* w2   = (const float*)d_in[12];
    const float* b2   = (const float*)d_in[13];
    float* out = (float*)d_out;

    unsigned short* wsq = (unsigned short*)d_ws;   // 319488 B used

    prep<<<dim3(624), dim3(256), 0, stream>>>(qkvw, pw, w1, w2, rpb, wsq);
    fused<<<dim3(8192), dim3(256), 0, stream>>>(x, n1w, n1b, qkvb, pb, n2w, n2b,
                                                b1, b2, wsq, out);
}

// Round 2
// 387.523 us; speedup vs baseline: 1.0452x; 1.0452x over previous
//
#include <hip/hip_runtime.h>
#include <math.h>

#define HH    256
#define WWID  256
#define WSZ   8
#define SSZ   4
#define NHEAD 3
#define CCH   96
#define DFF   384

#define XW_LD 104   // bf16 elems; 208 B rows
#define QK_LD 200   // 400 B rows (Q 0..95 -> O; K 96..191); reused as H[64][200]
#define VT_LD 72    // 144 B rows
#define H_LD  200

using bf16x8 = __attribute__((ext_vector_type(8))) short;
using f32x4  = __attribute__((ext_vector_type(4))) float;
using int2v  = __attribute__((ext_vector_type(2))) int;

#define LOG2E 1.44269504088896f

__device__ __forceinline__ unsigned short f2bf(float f) {   // prep only
    unsigned u = __float_as_uint(f);
    return (unsigned short)((u + 0x7FFFu + ((u >> 16) & 1u)) >> 16);
}
__device__ __forceinline__ float bf2f(unsigned short s) {
    return __uint_as_float(((unsigned)s) << 16);
}
// HW packed f32->bf16 (RNE): 1 VOP3 per pair. lo -> bits[15:0], hi -> bits[31:16].
__device__ __forceinline__ unsigned cvtpk(float lo, float hi) {
    unsigned r;
    asm("v_cvt_pk_bf16_f32 %0, %1, %2" : "=v"(r) : "v"(lo), "v"(hi));
    return r;
}
__device__ __forceinline__ float lo2f(unsigned u) { return __uint_as_float(u << 16); }
__device__ __forceinline__ float hi2f(unsigned u) { return __uint_as_float(u & 0xFFFF0000u); }

__device__ __forceinline__ float gelu_t(float t) {
    float t2 = t * t;
    float u  = t * (0.7978845608028654f + 0.03567740814183f * t2);
    float e  = exp2f(u * 2.885390081777927f);
    float rc = __builtin_amdgcn_rcpf(e + 1.f);
    return t - t * rc;
}

// ---------------- workspace: bf16 packs + combined bias/mask table ----------------
#define WQ_OFF  0
#define WP_OFF  27648
#define W1_OFF  36864
#define W2_OFF  73728
#define CT_OFF  110592

// frag(tile t, kstep s, lane l, j) = W[t*16 + l%16][s*32 + (l/16)*8 + j]
__global__ void __launch_bounds__(256)
prep(const float* __restrict__ qkvw, const float* __restrict__ pw,
     const float* __restrict__ w1, const float* __restrict__ w2,
     const float* __restrict__ rpb, unsigned short* __restrict__ wsq)
{
    int e = blockIdx.x * 256 + threadIdx.x;
    if (e < 110592) {
        const float* W; int Kd, nk, i = e;
        if (i < 27648)      { W = qkvw; Kd = 96;  nk = 3;  }
        else if (i < 36864) { W = pw;   Kd = 96;  nk = 3;  i -= 27648; }
        else if (i < 73728) { W = w1;   Kd = 96;  nk = 3;  i -= 36864; }
        else                { W = w2;   Kd = 384; nk = 12; i -= 73728; }
        int j = i & 7, fe = i >> 3;
        int lane = fe & 63, q = fe >> 6;
        int ks = q % nk, t = q / nk;
        int row = t * 16 + (lane & 15);
        int col = ks * 32 + (lane >> 4) * 8 + j;
        wsq[e] = f2bf(W[(size_t)row * Kd + col]);
    } else if (e < 159744) {
        int i = e - 110592;
        int cls = i / 12288;
        int rem = i - cls * 12288;
        int h = rem >> 12, n = (rem >> 6) & 63, m = rem & 63;
        int rel = ((n >> 3) - (m >> 3) + 7) * 15 + ((n & 7) - (m & 7) + 7);
        float bias = rpb[rel * NHEAD + h];
        int ci = cls >> 1, cj = cls & 1;
        int rn = (ci ? ((n >> 3) < 4 ? 1 : 2) : 0) * 3 + (cj ? ((n & 7) < 4 ? 1 : 2) : 0);
        int rm = (ci ? ((m >> 3) < 4 ? 1 : 2) : 0) * 3 + (cj ? ((m & 7) < 4 ? 1 : 2) : 0);
        float mask = (rn != rm) ? -100.f : 0.f;
        wsq[CT_OFF + i] = f2bf((bias + mask) * LOG2E);
    }
}

// ---------------- Fused block. LDS 39424 B -> 4 blocks/CU (LDS-capped; NO waves-per-EU
// hint: (256,4) made the backend clamp arch VGPRs to 64 and spill ~600 MB/dispatch).
// P-transpose fully in registers (permlane32_swap + ds_swizzle xor16), sP eliminated.
__global__ void __launch_bounds__(256)
fused(const float* __restrict__ x,
      const float* __restrict__ n1w, const float* __restrict__ n1b,
      const float* __restrict__ qkvb, const float* __restrict__ pb,
      const float* __restrict__ n2w, const float* __restrict__ n2b,
      const float* __restrict__ b1, const float* __restrict__ b2,
      const unsigned short* __restrict__ wsq,
      float* __restrict__ y)
{
    __shared__ unsigned short SM[19712];           // 39424 B
    unsigned short* sR1 = SM;                      // XW -> VT -> proj-out -> XN -> mlp-out
    unsigned short* sQK = SM + 6912;               // QK[64][200] -> H[64][200]

    const int bwin = blockIdx.x;
    const int b  = bwin >> 10;
    const int wi = (bwin >> 5) & 31;
    const int wj = bwin & 31;
    const int tid = threadIdx.x;
    const int lane = tid & 63;
    const int wave = tid >> 6;
    const int l15 = lane & 15;
    const int l16 = lane >> 4;
    const int nb = wave * 16;
    const int sub = lane & 3;

    // token-major identity: this lane covers token tm = nb + (lane>>2), channels sub*24..+23
    const int tm  = nb + (lane >> 2);
    const int gh1 = ((wi << 3) + (tm >> 3) + SSZ) & (HH - 1);
    const int gw1 = ((wj << 3) + (tm & 7) + SSZ) & (WWID - 1);
    const size_t rowtm = ((size_t)b * (HH * WWID) + (size_t)gh1 * WWID + gw1) * CCH;

    // ---- Phase 1: load x (kept in regs), LN1, XW -> LDS ----
    f32x4 xv[6];
    {
        const float* xr = x + rowtm + sub * 24;
#pragma unroll
        for (int q = 0; q < 6; ++q) xv[q] = *(const f32x4*)(xr + 4 * q);
        float s1 = 0.f, s2 = 0.f;
#pragma unroll
        for (int q = 0; q < 6; ++q)
#pragma unroll
            for (int r = 0; r < 4; ++r) { s1 += xv[q][r]; s2 = fmaf(xv[q][r], xv[q][r], s2); }
        s1 += __shfl_xor(s1, 1);  s2 += __shfl_xor(s2, 1);
        s1 += __shfl_xor(s1, 2);  s2 += __shfl_xor(s2, 2);
        const float mean = s1 * (1.f / CCH);
        const float rstd = rsqrtf(s2 * (1.f / CCH) - mean * mean + 1e-5f);
        unsigned o[12];
#pragma unroll
        for (int q = 0; q < 6; ++q) {
            const f32x4 wv = *(const f32x4*)&n1w[sub * 24 + 4 * q];
            const f32x4 bv = *(const f32x4*)&n1b[sub * 24 + 4 * q];
            float a0 = (xv[q][0] - mean) * rstd * wv[0] + bv[0];
            float a1 = (xv[q][1] - mean) * rstd * wv[1] + bv[1];
            float a2 = (xv[q][2] - mean) * rstd * wv[2] + bv[2];
            float a3 = (xv[q][3] - mean) * rstd * wv[3] + bv[3];
            o[2 * q] = cvtpk(a0, a1); o[2 * q + 1] = cvtpk(a2, a3);
        }
        unsigned* dst = (unsigned*)&sR1[tm * XW_LD + sub * 24];
#pragma unroll
        for (int q = 0; q < 3; ++q) {
            uint4 u; u.x = o[4 * q]; u.y = o[4 * q + 1]; u.z = o[4 * q + 2]; u.w = o[4 * q + 3];
            *(uint4*)(dst + 4 * q) = u;
        }
    }
    __syncthreads();   // B1: XW complete (all rows)

    // A-frags for ALL 4 row-tiles (N-split needs full M in regs)
    bf16x8 afr[4][3];
#pragma unroll
    for (int mt = 0; mt < 4; ++mt)
#pragma unroll
        for (int ks = 0; ks < 3; ++ks)
            afr[mt][ks] = *(const bf16x8*)&sR1[(mt * 16 + l15) * XW_LD + ks * 32 + l16 * 8];
    __syncthreads();   // B1b: XW fully read; sR1 becomes VT

    // ---- Phase 2: QKV N-split (each weight tile loaded by ONE wave, feeds 4 MFMAs) ----
    {
        const float qscale = 0.17677669529663689f * LOG2E;
        for (int nt = wave; nt < 18; nt += 4) {
            f32x4 acc[4] = {{0,0,0,0},{0,0,0,0},{0,0,0,0},{0,0,0,0}};
#pragma unroll
            for (int ks = 0; ks < 3; ++ks) {
                const bf16x8 wf = *(const bf16x8*)(wsq + ((size_t)(nt * 3 + ks) * 64 + lane) * 8);
#pragma unroll
                for (int mt = 0; mt < 4; ++mt)
                    acc[mt] = __builtin_amdgcn_mfma_f32_16x16x32_bf16(wf, afr[mt][ks], acc[mt], 0, 0, 0);
            }
            const f32x4 bias = *(const f32x4*)&qkvb[nt * 16 + 4 * l16];
            if (nt < 6) {
#pragma unroll
                for (int mt = 0; mt < 4; ++mt) {
                    uint2 u;
                    u.x = cvtpk((acc[mt][0] + bias[0]) * qscale, (acc[mt][1] + bias[1]) * qscale);
                    u.y = cvtpk((acc[mt][2] + bias[2]) * qscale, (acc[mt][3] + bias[3]) * qscale);
                    *(uint2*)&sQK[(mt * 16 + l15) * QK_LD + nt * 16 + 4 * l16] = u;
                }
            } else if (nt < 12) {
#pragma unroll
                for (int mt = 0; mt < 4; ++mt) {
                    uint2 u;
                    u.x = cvtpk(acc[mt][0] + bias[0], acc[mt][1] + bias[1]);
                    u.y = cvtpk(acc[mt][2] + bias[2], acc[mt][3] + bias[3]);
                    *(uint2*)&sQK[(mt * 16 + l15) * QK_LD + nt * 16 + 4 * l16] = u;
                }
            } else {
                const int ch = nt * 16 - 192 + 4 * l16;
#pragma unroll
                for (int mt = 0; mt < 4; ++mt) {
                    const unsigned v01 = cvtpk(acc[mt][0] + bias[0], acc[mt][1] + bias[1]);
                    const unsigned v23 = cvtpk(acc[mt][2] + bias[2], acc[mt][3] + bias[3]);
                    sR1[(ch + 0) * VT_LD + mt * 16 + l15] = (unsigned short)v01;
                    sR1[(ch + 1) * VT_LD + mt * 16 + l15] = (unsigned short)(v01 >> 16);
                    sR1[(ch + 2) * VT_LD + mt * 16 + l15] = (unsigned short)v23;
                    sR1[(ch + 3) * VT_LD + mt * 16 + l15] = (unsigned short)(v23 >> 16);
                }
            }
        }
    }
    __syncthreads();   // B2: Q, K, V visible to all waves

    // ---- Phase 3: attention, M-split, in-register P transpose (no sP) ----
    // C-layout after mfma(kf,qf): lane(g=l16,t=l15) holds P[n=t][m = mt*16 + g*4 + r].
    // B-frag needs lane(g,t): P[n=t][m = ks*32 + g*8 + j], j=0..7.
    // With A_q=u[2ks][q], B_q=u[2ks+1][q]: (X,Y)=permlane32_swap(A,B) gives
    //   X = {A.lo | B.lo}, Y = {A.hi | B.hi}; S* = xor16-swizzle.
    // even g: pf = {X0,X1,SX0,SX1}; odd g: pf = {SY0,SY1,Y0,Y1}.
    {
        const int cls = ((wi == 31) ? 2 : 0) + ((wj == 31) ? 1 : 0);
        const unsigned short* ctb = wsq + CT_OFF + cls * 12288;
        const bool godd = (l16 & 1) != 0;
#pragma unroll 1
        for (int h = 0; h < NHEAD; ++h) {
            const bf16x8 qf = *(const bf16x8*)&sQK[(nb + l15) * QK_LD + h * 32 + l16 * 8];
            f32x4 s[4];
#pragma unroll
            for (int mt = 0; mt < 4; ++mt) {
                const bf16x8 kf = *(const bf16x8*)&sQK[(mt * 16 + l15) * QK_LD + CCH + h * 32 + l16 * 8];
                f32x4 z = {0, 0, 0, 0};
                s[mt] = __builtin_amdgcn_mfma_f32_16x16x32_bf16(kf, qf, z, 0, 0, 0);
            }
            const unsigned short* cth = ctb + h * 4096 + (nb + l15) * 64;
            unsigned u[4][2];
            float rsum = 0.f;
#pragma unroll
            for (int mt = 0; mt < 4; ++mt) {
                const ushort4 c4 = *(const ushort4*)&cth[mt * 16 + 4 * l16];
                const float pv0 = exp2f(s[mt][0] + bf2f(c4.x));
                const float pv1 = exp2f(s[mt][1] + bf2f(c4.y));
                const float pv2 = exp2f(s[mt][2] + bf2f(c4.z));
                const float pv3 = exp2f(s[mt][3] + bf2f(c4.w));
                rsum += pv0 + pv1 + pv2 + pv3;
                u[mt][0] = cvtpk(pv0, pv1);
                u[mt][1] = cvtpk(pv2, pv3);
            }
            rsum += __shfl_xor(rsum, 16);
            rsum += __shfl_xor(rsum, 32);
            const float rinv = __builtin_amdgcn_rcpf(rsum);
            f32x4 o[2] = {{0,0,0,0},{0,0,0,0}};
#pragma unroll
            for (int ks = 0; ks < 2; ++ks) {
                const int2v r0 = __builtin_amdgcn_permlane32_swap(
                    (int)u[2 * ks][0], (int)u[2 * ks + 1][0], false, false);
                const int2v r1 = __builtin_amdgcn_permlane32_swap(
                    (int)u[2 * ks][1], (int)u[2 * ks + 1][1], false, false);
                const unsigned X0 = (unsigned)r0[0], Y0 = (unsigned)r0[1];
                const unsigned X1 = (unsigned)r1[0], Y1 = (unsigned)r1[1];
                const unsigned SX0 = (unsigned)__builtin_amdgcn_ds_swizzle((int)X0, 0x401F);
                const unsigned SX1 = (unsigned)__builtin_amdgcn_ds_swizzle((int)X1, 0x401F);
                const unsigned SY0 = (unsigned)__builtin_amdgcn_ds_swizzle((int)Y0, 0x401F);
                const unsigned SY1 = (unsigned)__builtin_amdgcn_ds_swizzle((int)Y1, 0x401F);
                union { unsigned w[4]; bf16x8 v; } pk;
                pk.w[0] = godd ? SY0 : X0;
                pk.w[1] = godd ? SY1 : X1;
                pk.w[2] = godd ? Y0 : SX0;
                pk.w[3] = godd ? Y1 : SX1;
#pragma unroll
                for (int dt = 0; dt < 2; ++dt) {
                    const bf16x8 vf = *(const bf16x8*)&sR1[(h * 32 + dt * 16 + l15) * VT_LD + ks * 32 + l16 * 8];
                    o[dt] = __builtin_amdgcn_mfma_f32_16x16x32_bf16(vf, pk.v, o[dt], 0, 0, 0);
                }
            }
#pragma unroll
            for (int dt = 0; dt < 2; ++dt) {
                uint2 uo;
                uo.x = cvtpk(o[dt][0] * rinv, o[dt][1] * rinv);
                uo.y = cvtpk(o[dt][2] * rinv, o[dt][3] * rinv);
                *(uint2*)&sQK[(nb + l15) * QK_LD + h * 32 + dt * 16 + 4 * l16] = uo;
            }
        }
    }
    __syncthreads();   // B3: O complete (all rows); VT fully consumed

    // ---- Phase 4: proj N-split -> proj-out chan-major (all rows) ----
    {
        bf16x8 ofr[4][3];
#pragma unroll
        for (int mt = 0; mt < 4; ++mt)
#pragma unroll
            for (int ks = 0; ks < 3; ++ks)
                ofr[mt][ks] = *(const bf16x8*)&sQK[(mt * 16 + l15) * QK_LD + ks * 32 + l16 * 8];
        const unsigned short* wp = wsq + WP_OFF;
        for (int ct = wave; ct < 6; ct += 4) {
            f32x4 acc[4] = {{0,0,0,0},{0,0,0,0},{0,0,0,0},{0,0,0,0}};
#pragma unroll
            for (int ks = 0; ks < 3; ++ks) {
                const bf16x8 wf = *(const bf16x8*)(wp + ((size_t)(ct * 3 + ks) * 64 + lane) * 8);
#pragma unroll
                for (int mt = 0; mt < 4; ++mt)
                    acc[mt] = __builtin_amdgcn_mfma_f32_16x16x32_bf16(wf, ofr[mt][ks], acc[mt], 0, 0, 0);
            }
            const f32x4 pbv = *(const f32x4*)&pb[ct * 16 + 4 * l16];
#pragma unroll
            for (int mt = 0; mt < 4; ++mt) {
                uint2 u;
                u.x = cvtpk(acc[mt][0] + pbv[0], acc[mt][1] + pbv[1]);
                u.y = cvtpk(acc[mt][2] + pbv[2], acc[mt][3] + pbv[3]);
                *(uint2*)&sR1[(mt * 16 + l15) * XW_LD + ct * 16 + 4 * l16] = u;
            }
        }
    }
    __syncthreads();   // B4: proj-out complete

    // ---- Phase 5: residual + LN2 (token-major regs); XN -> LDS (own rows) ----
    float y1tm[6][4];
    {
        const unsigned* src = (const unsigned*)&sR1[tm * XW_LD + sub * 24];
#pragma unroll
        for (int q3 = 0; q3 < 3; ++q3) {
            const uint4 u = *(const uint4*)(src + 4 * q3);
            y1tm[2 * q3][0]     = xv[2 * q3][0] + lo2f(u.x);
            y1tm[2 * q3][1]     = xv[2 * q3][1] + hi2f(u.x);
            y1tm[2 * q3][2]     = xv[2 * q3][2] + lo2f(u.y);
            y1tm[2 * q3][3]     = xv[2 * q3][3] + hi2f(u.y);
            y1tm[2 * q3 + 1][0] = xv[2 * q3 + 1][0] + lo2f(u.z);
            y1tm[2 * q3 + 1][1] = xv[2 * q3 + 1][1] + hi2f(u.z);
            y1tm[2 * q3 + 1][2] = xv[2 * q3 + 1][2] + lo2f(u.w);
            y1tm[2 * q3 + 1][3] = xv[2 * q3 + 1][3] + hi2f(u.w);
        }
        float s1 = 0.f, s2 = 0.f;
#pragma unroll
        for (int q = 0; q < 6; ++q)
#pragma unroll
            for (int r = 0; r < 4; ++r) { s1 += y1tm[q][r]; s2 = fmaf(y1tm[q][r], y1tm[q][r], s2); }
        s1 += __shfl_xor(s1, 1);  s2 += __shfl_xor(s2, 1);
        s1 += __shfl_xor(s1, 2);  s2 += __shfl_xor(s2, 2);
        const float mean = s1 * (1.f / CCH);
        const float rstd = rsqrtf(s2 * (1.f / CCH) - mean * mean + 1e-5f);
        unsigned o[12];
#pragma unroll
        for (int q = 0; q < 6; ++q) {
            const f32x4 wv = *(const f32x4*)&n2w[sub * 24 + 4 * q];
            const f32x4 bv = *(const f32x4*)&n2b[sub * 24 + 4 * q];
            float a0 = (y1tm[q][0] - mean) * rstd * wv[0] + bv[0];
            float a1 = (y1tm[q][1] - mean) * rstd * wv[1] + bv[1];
            float a2 = (y1tm[q][2] - mean) * rstd * wv[2] + bv[2];
            float a3 = (y1tm[q][3] - mean) * rstd * wv[3] + bv[3];
            o[2 * q] = cvtpk(a0, a1); o[2 * q + 1] = cvtpk(a2, a3);
        }
        unsigned* dst = (unsigned*)&sR1[tm * XW_LD + sub * 24];
#pragma unroll
        for (int q = 0; q < 3; ++q) {
            uint4 u; u.x = o[4 * q]; u.y = o[4 * q + 1]; u.z = o[4 * q + 2]; u.w = o[4 * q + 3];
            *(uint4*)(dst + 4 * q) = u;
        }
    }
    __syncthreads();   // B5: XN complete (all rows)

    bf16x8 xfr[4][3];
#pragma unroll
    for (int mt = 0; mt < 4; ++mt)
#pragma unroll
        for (int ks = 0; ks < 3; ++ks)
            xfr[mt][ks] = *(const bf16x8*)&sR1[(mt * 16 + l15) * XW_LD + ks * 32 + l16 * 8];

    // ---- Phase 6: MLP N-split, H in halves, persistent acc2[cti][mt] ----
    f32x4 acc2[2][4];
#pragma unroll
    for (int ci = 0; ci < 2; ++ci)
#pragma unroll
        for (int mt = 0; mt < 4; ++mt) acc2[ci][mt] = (f32x4){0, 0, 0, 0};
    const unsigned short* w2p = wsq + W2_OFF;
#pragma unroll 1
    for (int half = 0; half < 2; ++half) {
        const unsigned short* w1p = wsq + W1_OFF + (size_t)half * 12 * 3 * 64 * 8;
        for (int nt = wave; nt < 12; nt += 4) {
            f32x4 acc[4] = {{0,0,0,0},{0,0,0,0},{0,0,0,0},{0,0,0,0}};
#pragma unroll
            for (int ks = 0; ks < 3; ++ks) {
                const bf16x8 wf = *(const bf16x8*)(w1p + ((size_t)(nt * 3 + ks) * 64 + lane) * 8);
#pragma unroll
                for (int mt = 0; mt < 4; ++mt)
                    acc[mt] = __builtin_amdgcn_mfma_f32_16x16x32_bf16(wf, xfr[mt][ks], acc[mt], 0, 0, 0);
            }
            const f32x4 b1v = *(const f32x4*)&b1[(half * 12 + nt) * 16 + 4 * l16];
#pragma unroll
            for (int mt = 0; mt < 4; ++mt) {
                uint2 u;
                u.x = cvtpk(gelu_t(acc[mt][0] + b1v[0]), gelu_t(acc[mt][1] + b1v[1]));
                u.y = cvtpk(gelu_t(acc[mt][2] + b1v[2]), gelu_t(acc[mt][3] + b1v[3]));
                *(uint2*)&sQK[(mt * 16 + l15) * H_LD + nt * 16 + 4 * l16] = u;
            }
        }
        __syncthreads();   // H(half) complete
#pragma unroll
        for (int k6 = 0; k6 < 6; ++k6) {
            bf16x8 hfr[4];
#pragma unroll
            for (int mt = 0; mt < 4; ++mt)
                hfr[mt] = *(const bf16x8*)&sQK[(mt * 16 + l15) * H_LD + k6 * 32 + l16 * 8];
#pragma unroll
            for (int ci = 0; ci < 2; ++ci) {
                const int ct = wave + 4 * ci;
                if (ct < 6) {
                    const bf16x8 wf = *(const bf16x8*)(w2p + ((size_t)(ct * 12 + half * 6 + k6) * 64 + lane) * 8);
#pragma unroll
                    for (int mt = 0; mt < 4; ++mt)
                        acc2[ci][mt] = __builtin_amdgcn_mfma_f32_16x16x32_bf16(wf, hfr[mt], acc2[ci][mt], 0, 0, 0);
                }
            }
        }
        if (half == 0) __syncthreads();   // H consumed before overwrite
    }

    // ---- Final: mlp-out chan-major (all rows) -> B8 -> token-major +y1, coalesced store ----
    {
#pragma unroll
        for (int ci = 0; ci < 2; ++ci) {
            const int ct = wave + 4 * ci;
            if (ct < 6) {
                const f32x4 b2v = *(const f32x4*)&b2[ct * 16 + 4 * l16];
#pragma unroll
                for (int mt = 0; mt < 4; ++mt) {
                    uint2 u;
                    u.x = cvtpk(acc2[ci][mt][0] + b2v[0], acc2[ci][mt][1] + b2v[1]);
                    u.y = cvtpk(acc2[ci][mt][2] + b2v[2], acc2[ci][mt][3] + b2v[3]);
                    *(uint2*)&sR1[(mt * 16 + l15) * XW_LD + ct * 16 + 4 * l16] = u;
                }
            }
        }
    }
    __syncthreads();   // B8: mlp-out complete
    {
        const unsigned* src = (const unsigned*)&sR1[tm * XW_LD + sub * 24];
        float* yr = y + rowtm + sub * 24;
#pragma unroll
        for (int q3 = 0; q3 < 3; ++q3) {
            const uint4 u = *(const uint4*)(src + 4 * q3);
            f32x4 o0, o1;
            o0[0] = y1tm[2 * q3][0] + lo2f(u.x);
            o0[1] = y1tm[2 * q3][1] + hi2f(u.x);
            o0[2] = y1tm[2 * q3][2] + lo2f(u.y);
            o0[3] = y1tm[2 * q3][3] + hi2f(u.y);
            o1[0] = y1tm[2 * q3 + 1][0] + lo2f(u.z);
            o1[1] = y1tm[2 * q3 + 1][1] + hi2f(u.z);
            o1[2] = y1tm[2 * q3 + 1][2] + lo2f(u.w);
            o1[3] = y1tm[2 * q3 + 1][3] + hi2f(u.w);
            *(f32x4*)(yr + 8 * q3)     = o0;
            *(f32x4*)(yr + 8 * q3 + 4) = o1;
        }
    }
}

extern "C" void kernel_launch(void* const* d_in, const int* in_sizes, int n_in,
                              void* d_out, int out_size, void* d_ws, size_t ws_size,
                              hipStream_t stream)
{
    const float* x    = (const float*)d_in[0];
    const float* n1w  = (const float*)d_in[1];
    const float* n1b  = (const float*)d_in[2];
    const float* qkvw = (const float*)d_in[3];
    const float* qkvb = (const float*)d_in[4];
    const float* rpb  = (const float*)d_in[5];
    const float* pw   = (const float*)d_in[6];
    const float* pb   = (const float*)d_in[7];
    const float* n2w  = (const float*)d_in[8];
    const float* n2b  = (const float*)d_in[9];
    const float* w1   = (const float*)d_in[10];
    const float* b1   = (const float*)d_in[11];
    const float* w2   = (const float*)d_in[12];
    const float* b2   = (const float*)d_in[13];
    float* out = (float*)d_out;

    unsigned short* wsq = (unsigned short*)d_ws;   // 319488 B used

    prep<<<dim3(624), dim3(256), 0, stream>>>(qkvw, pw, w1, w2, rpb, wsq);
    fused<<<dim3(8192), dim3(256), 0, stream>>>(x, n1w, n1b, qkvb, pb, n2w, n2b,
                                                b1, b2, wsq, out);
}

// Round 3
// 318.627 us; speedup vs baseline: 1.2712x; 1.2162x over previous
//
#include <hip/hip_runtime.h>
#include <math.h>

#define HH    256
#define WWID  256
#define WSZ   8
#define SSZ   4
#define NHEAD 3
#define CCH   96
#define DFF   384

#define XW_LD 104   // bf16 elems; 208 B rows
#define QK_LD 200   // 400 B rows (Q 0..95 -> O; K 96..191); reused as H[64][200]
#define VT_LD 72    // 144 B rows
#define H_LD  200

using bf16x8 = __attribute__((ext_vector_type(8))) short;
using f32x4  = __attribute__((ext_vector_type(4))) float;
using int2v  = __attribute__((ext_vector_type(2))) int;

#define LOG2E 1.44269504088896f

__device__ __forceinline__ unsigned short f2bf(float f) {   // prep only
    unsigned u = __float_as_uint(f);
    return (unsigned short)((u + 0x7FFFu + ((u >> 16) & 1u)) >> 16);
}
__device__ __forceinline__ float bf2f(unsigned short s) {
    return __uint_as_float(((unsigned)s) << 16);
}
// HW packed f32->bf16 (RNE): 1 VOP3 per pair. lo -> bits[15:0], hi -> bits[31:16].
__device__ __forceinline__ unsigned cvtpk(float lo, float hi) {
    unsigned r;
    asm("v_cvt_pk_bf16_f32 %0, %1, %2" : "=v"(r) : "v"(lo), "v"(hi));
    return r;
}
__device__ __forceinline__ float lo2f(unsigned u) { return __uint_as_float(u << 16); }
__device__ __forceinline__ float hi2f(unsigned u) { return __uint_as_float(u & 0xFFFF0000u); }

__device__ __forceinline__ float gelu_t(float t) {
    float t2 = t * t;
    float u  = t * (0.7978845608028654f + 0.03567740814183f * t2);
    float e  = exp2f(u * 2.885390081777927f);
    float rc = __builtin_amdgcn_rcpf(e + 1.f);
    return t - t * rc;
}

// ---------------- workspace: bf16 packs + combined bias/mask table ----------------
#define WQ_OFF  0
#define WP_OFF  27648
#define W1_OFF  36864
#define W2_OFF  73728
#define CT_OFF  110592

// frag(tile t, kstep s, lane l, j) = W[t*16 + l%16][s*32 + (l/16)*8 + j]
__global__ void __launch_bounds__(256)
prep(const float* __restrict__ qkvw, const float* __restrict__ pw,
     const float* __restrict__ w1, const float* __restrict__ w2,
     const float* __restrict__ rpb, unsigned short* __restrict__ wsq)
{
    int e = blockIdx.x * 256 + threadIdx.x;
    if (e < 110592) {
        const float* W; int Kd, nk, i = e;
        if (i < 27648)      { W = qkvw; Kd = 96;  nk = 3;  }
        else if (i < 36864) { W = pw;   Kd = 96;  nk = 3;  i -= 27648; }
        else if (i < 73728) { W = w1;   Kd = 96;  nk = 3;  i -= 36864; }
        else                { W = w2;   Kd = 384; nk = 12; i -= 73728; }
        int j = i & 7, fe = i >> 3;
        int lane = fe & 63, q = fe >> 6;
        int ks = q % nk, t = q / nk;
        int row = t * 16 + (lane & 15);
        int col = ks * 32 + (lane >> 4) * 8 + j;
        wsq[e] = f2bf(W[(size_t)row * Kd + col]);
    } else if (e < 159744) {
        int i = e - 110592;
        int cls = i / 12288;
        int rem = i - cls * 12288;
        int h = rem >> 12, n = (rem >> 6) & 63, m = rem & 63;
        int rel = ((n >> 3) - (m >> 3) + 7) * 15 + ((n & 7) - (m & 7) + 7);
        float bias = rpb[rel * NHEAD + h];
        int ci = cls >> 1, cj = cls & 1;
        int rn = (ci ? ((n >> 3) < 4 ? 1 : 2) : 0) * 3 + (cj ? ((n & 7) < 4 ? 1 : 2) : 0);
        int rm = (ci ? ((m >> 3) < 4 ? 1 : 2) : 0) * 3 + (cj ? ((m & 7) < 4 ? 1 : 2) : 0);
        float mask = (rn != rm) ? -100.f : 0.f;
        wsq[CT_OFF + i] = f2bf((bias + mask) * LOG2E);
    }
}

// ---------------- Fused block. LDS 39424 B (4 blocks/CU LDS-cap).
// __launch_bounds__(256,3): cap total VGPR+AGPR at ~170/wave (Round-0 demand ~148 fits;
// (256,4) clamped arch regs to 64 -> 600 MB scratch spills; no hint -> ~200 total -> 2 blk/CU).
// P-transpose fully in registers (permlane32_swap + ds_swizzle xor16), sP eliminated.
// Phase-6 W1 re-reads XN frags from LDS per (nt,ks) instead of holding xfr[4][3] (peak -32 regs).
__global__ void __launch_bounds__(256, 3)
fused(const float* __restrict__ x,
      const float* __restrict__ n1w, const float* __restrict__ n1b,
      const float* __restrict__ qkvb, const float* __restrict__ pb,
      const float* __restrict__ n2w, const float* __restrict__ n2b,
      const float* __restrict__ b1, const float* __restrict__ b2,
      const unsigned short* __restrict__ wsq,
      float* __restrict__ y)
{
    __shared__ unsigned short SM[19712];           // 39424 B
    unsigned short* sR1 = SM;                      // XW -> VT -> proj-out -> XN -> mlp-out
    unsigned short* sQK = SM + 6912;               // QK[64][200] -> H[64][200]

    const int bwin = blockIdx.x;
    const int b  = bwin >> 10;
    const int wi = (bwin >> 5) & 31;
    const int wj = bwin & 31;
    const int tid = threadIdx.x;
    const int lane = tid & 63;
    const int wave = tid >> 6;
    const int l15 = lane & 15;
    const int l16 = lane >> 4;
    const int nb = wave * 16;
    const int sub = lane & 3;

    // token-major identity: this lane covers token tm = nb + (lane>>2), channels sub*24..+23
    const int tm  = nb + (lane >> 2);
    const int gh1 = ((wi << 3) + (tm >> 3) + SSZ) & (HH - 1);
    const int gw1 = ((wj << 3) + (tm & 7) + SSZ) & (WWID - 1);
    const size_t rowtm = ((size_t)b * (HH * WWID) + (size_t)gh1 * WWID + gw1) * CCH;

    // ---- Phase 1: load x (kept in regs), LN1, XW -> LDS ----
    f32x4 xv[6];
    {
        const float* xr = x + rowtm + sub * 24;
#pragma unroll
        for (int q = 0; q < 6; ++q) xv[q] = *(const f32x4*)(xr + 4 * q);
        float s1 = 0.f, s2 = 0.f;
#pragma unroll
        for (int q = 0; q < 6; ++q)
#pragma unroll
            for (int r = 0; r < 4; ++r) { s1 += xv[q][r]; s2 = fmaf(xv[q][r], xv[q][r], s2); }
        s1 += __shfl_xor(s1, 1);  s2 += __shfl_xor(s2, 1);
        s1 += __shfl_xor(s1, 2);  s2 += __shfl_xor(s2, 2);
        const float mean = s1 * (1.f / CCH);
        const float rstd = rsqrtf(s2 * (1.f / CCH) - mean * mean + 1e-5f);
        unsigned o[12];
#pragma unroll
        for (int q = 0; q < 6; ++q) {
            const f32x4 wv = *(const f32x4*)&n1w[sub * 24 + 4 * q];
            const f32x4 bv = *(const f32x4*)&n1b[sub * 24 + 4 * q];
            float a0 = (xv[q][0] - mean) * rstd * wv[0] + bv[0];
            float a1 = (xv[q][1] - mean) * rstd * wv[1] + bv[1];
            float a2 = (xv[q][2] - mean) * rstd * wv[2] + bv[2];
            float a3 = (xv[q][3] - mean) * rstd * wv[3] + bv[3];
            o[2 * q] = cvtpk(a0, a1); o[2 * q + 1] = cvtpk(a2, a3);
        }
        unsigned* dst = (unsigned*)&sR1[tm * XW_LD + sub * 24];
#pragma unroll
        for (int q = 0; q < 3; ++q) {
            uint4 u; u.x = o[4 * q]; u.y = o[4 * q + 1]; u.z = o[4 * q + 2]; u.w = o[4 * q + 3];
            *(uint4*)(dst + 4 * q) = u;
        }
    }
    __syncthreads();   // B1: XW complete (all rows)

    // A-frags for ALL 4 row-tiles (N-split needs full M in regs)
    bf16x8 afr[4][3];
#pragma unroll
    for (int mt = 0; mt < 4; ++mt)
#pragma unroll
        for (int ks = 0; ks < 3; ++ks)
            afr[mt][ks] = *(const bf16x8*)&sR1[(mt * 16 + l15) * XW_LD + ks * 32 + l16 * 8];
    __syncthreads();   // B1b: XW fully read; sR1 becomes VT

    // ---- Phase 2: QKV N-split (each weight tile loaded by ONE wave, feeds 4 MFMAs) ----
    {
        const float qscale = 0.17677669529663689f * LOG2E;
        for (int nt = wave; nt < 18; nt += 4) {
            f32x4 acc[4] = {{0,0,0,0},{0,0,0,0},{0,0,0,0},{0,0,0,0}};
#pragma unroll
            for (int ks = 0; ks < 3; ++ks) {
                const bf16x8 wf = *(const bf16x8*)(wsq + ((size_t)(nt * 3 + ks) * 64 + lane) * 8);
#pragma unroll
                for (int mt = 0; mt < 4; ++mt)
                    acc[mt] = __builtin_amdgcn_mfma_f32_16x16x32_bf16(wf, afr[mt][ks], acc[mt], 0, 0, 0);
            }
            const f32x4 bias = *(const f32x4*)&qkvb[nt * 16 + 4 * l16];
            if (nt < 6) {
#pragma unroll
                for (int mt = 0; mt < 4; ++mt) {
                    uint2 u;
                    u.x = cvtpk((acc[mt][0] + bias[0]) * qscale, (acc[mt][1] + bias[1]) * qscale);
                    u.y = cvtpk((acc[mt][2] + bias[2]) * qscale, (acc[mt][3] + bias[3]) * qscale);
                    *(uint2*)&sQK[(mt * 16 + l15) * QK_LD + nt * 16 + 4 * l16] = u;
                }
            } else if (nt < 12) {
#pragma unroll
                for (int mt = 0; mt < 4; ++mt) {
                    uint2 u;
                    u.x = cvtpk(acc[mt][0] + bias[0], acc[mt][1] + bias[1]);
                    u.y = cvtpk(acc[mt][2] + bias[2], acc[mt][3] + bias[3]);
                    *(uint2*)&sQK[(mt * 16 + l15) * QK_LD + nt * 16 + 4 * l16] = u;
                }
            } else {
                const int ch = nt * 16 - 192 + 4 * l16;
#pragma unroll
                for (int mt = 0; mt < 4; ++mt) {
                    const unsigned v01 = cvtpk(acc[mt][0] + bias[0], acc[mt][1] + bias[1]);
                    const unsigned v23 = cvtpk(acc[mt][2] + bias[2], acc[mt][3] + bias[3]);
                    sR1[(ch + 0) * VT_LD + mt * 16 + l15] = (unsigned short)v01;
                    sR1[(ch + 1) * VT_LD + mt * 16 + l15] = (unsigned short)(v01 >> 16);
                    sR1[(ch + 2) * VT_LD + mt * 16 + l15] = (unsigned short)v23;
                    sR1[(ch + 3) * VT_LD + mt * 16 + l15] = (unsigned short)(v23 >> 16);
                }
            }
        }
    }
    __syncthreads();   // B2: Q, K, V visible to all waves

    // ---- Phase 3: attention, M-split, in-register P transpose (no sP) ----
    // C-layout after mfma(kf,qf): lane(g=l16,t=l15) holds P[n=t][m = mt*16 + g*4 + r].
    // B-frag needs lane(g,t): P[n=t][m = ks*32 + g*8 + j], j=0..7.
    // With A_q=u[2ks][q], B_q=u[2ks+1][q]: (X,Y)=permlane32_swap(A,B) gives
    //   X = {A.lo | B.lo}, Y = {A.hi | B.hi}; S* = xor16-swizzle.
    // even g: pf = {X0,X1,SX0,SX1}; odd g: pf = {SY0,SY1,Y0,Y1}.
    {
        const int cls = ((wi == 31) ? 2 : 0) + ((wj == 31) ? 1 : 0);
        const unsigned short* ctb = wsq + CT_OFF + cls * 12288;
        const bool godd = (l16 & 1) != 0;
#pragma unroll 1
        for (int h = 0; h < NHEAD; ++h) {
            const bf16x8 qf = *(const bf16x8*)&sQK[(nb + l15) * QK_LD + h * 32 + l16 * 8];
            f32x4 s[4];
#pragma unroll
            for (int mt = 0; mt < 4; ++mt) {
                const bf16x8 kf = *(const bf16x8*)&sQK[(mt * 16 + l15) * QK_LD + CCH + h * 32 + l16 * 8];
                f32x4 z = {0, 0, 0, 0};
                s[mt] = __builtin_amdgcn_mfma_f32_16x16x32_bf16(kf, qf, z, 0, 0, 0);
            }
            const unsigned short* cth = ctb + h * 4096 + (nb + l15) * 64;
            unsigned u[4][2];
            float rsum = 0.f;
#pragma unroll
            for (int mt = 0; mt < 4; ++mt) {
                const ushort4 c4 = *(const ushort4*)&cth[mt * 16 + 4 * l16];
                const float pv0 = exp2f(s[mt][0] + bf2f(c4.x));
                const float pv1 = exp2f(s[mt][1] + bf2f(c4.y));
                const float pv2 = exp2f(s[mt][2] + bf2f(c4.z));
                const float pv3 = exp2f(s[mt][3] + bf2f(c4.w));
                rsum += pv0 + pv1 + pv2 + pv3;
                u[mt][0] = cvtpk(pv0, pv1);
                u[mt][1] = cvtpk(pv2, pv3);
            }
            rsum += __shfl_xor(rsum, 16);
            rsum += __shfl_xor(rsum, 32);
            const float rinv = __builtin_amdgcn_rcpf(rsum);
            f32x4 o[2] = {{0,0,0,0},{0,0,0,0}};
#pragma unroll
            for (int ks = 0; ks < 2; ++ks) {
                const int2v r0 = __builtin_amdgcn_permlane32_swap(
                    (int)u[2 * ks][0], (int)u[2 * ks + 1][0], false, false);
                const int2v r1 = __builtin_amdgcn_permlane32_swap(
                    (int)u[2 * ks][1], (int)u[2 * ks + 1][1], false, false);
                const unsigned X0 = (unsigned)r0[0], Y0 = (unsigned)r0[1];
                const unsigned X1 = (unsigned)r1[0], Y1 = (unsigned)r1[1];
                const unsigned SX0 = (unsigned)__builtin_amdgcn_ds_swizzle((int)X0, 0x401F);
                const unsigned SX1 = (unsigned)__builtin_amdgcn_ds_swizzle((int)X1, 0x401F);
                const unsigned SY0 = (unsigned)__builtin_amdgcn_ds_swizzle((int)Y0, 0x401F);
                const unsigned SY1 = (unsigned)__builtin_amdgcn_ds_swizzle((int)Y1, 0x401F);
                union { unsigned w[4]; bf16x8 v; } pk;
                pk.w[0] = godd ? SY0 : X0;
                pk.w[1] = godd ? SY1 : X1;
                pk.w[2] = godd ? Y0 : SX0;
                pk.w[3] = godd ? Y1 : SX1;
#pragma unroll
                for (int dt = 0; dt < 2; ++dt) {
                    const bf16x8 vf = *(const bf16x8*)&sR1[(h * 32 + dt * 16 + l15) * VT_LD + ks * 32 + l16 * 8];
                    o[dt] = __builtin_amdgcn_mfma_f32_16x16x32_bf16(vf, pk.v, o[dt], 0, 0, 0);
                }
            }
#pragma unroll
            for (int dt = 0; dt < 2; ++dt) {
                uint2 uo;
                uo.x = cvtpk(o[dt][0] * rinv, o[dt][1] * rinv);
                uo.y = cvtpk(o[dt][2] * rinv, o[dt][3] * rinv);
                *(uint2*)&sQK[(nb + l15) * QK_LD + h * 32 + dt * 16 + 4 * l16] = uo;
            }
        }
    }
    __syncthreads();   // B3: O complete (all rows); VT fully consumed

    // ---- Phase 4: proj N-split -> proj-out chan-major (all rows) ----
    {
        bf16x8 ofr[4][3];
#pragma unroll
        for (int mt = 0; mt < 4; ++mt)
#pragma unroll
            for (int ks = 0; ks < 3; ++ks)
                ofr[mt][ks] = *(const bf16x8*)&sQK[(mt * 16 + l15) * QK_LD + ks * 32 + l16 * 8];
        const unsigned short* wp = wsq + WP_OFF;
        for (int ct = wave; ct < 6; ct += 4) {
            f32x4 acc[4] = {{0,0,0,0},{0,0,0,0},{0,0,0,0},{0,0,0,0}};
#pragma unroll
            for (int ks = 0; ks < 3; ++ks) {
                const bf16x8 wf = *(const bf16x8*)(wp + ((size_t)(ct * 3 + ks) * 64 + lane) * 8);
#pragma unroll
                for (int mt = 0; mt < 4; ++mt)
                    acc[mt] = __builtin_amdgcn_mfma_f32_16x16x32_bf16(wf, ofr[mt][ks], acc[mt], 0, 0, 0);
            }
            const f32x4 pbv = *(const f32x4*)&pb[ct * 16 + 4 * l16];
#pragma unroll
            for (int mt = 0; mt < 4; ++mt) {
                uint2 u;
                u.x = cvtpk(acc[mt][0] + pbv[0], acc[mt][1] + pbv[1]);
                u.y = cvtpk(acc[mt][2] + pbv[2], acc[mt][3] + pbv[3]);
                *(uint2*)&sR1[(mt * 16 + l15) * XW_LD + ct * 16 + 4 * l16] = u;
            }
        }
    }
    __syncthreads();   // B4: proj-out complete

    // ---- Phase 5: residual + LN2 (token-major regs); XN -> LDS (own rows) ----
    float y1tm[6][4];
    {
        const unsigned* src = (const unsigned*)&sR1[tm * XW_LD + sub * 24];
#pragma unroll
        for (int q3 = 0; q3 < 3; ++q3) {
            const uint4 u = *(const uint4*)(src + 4 * q3);
            y1tm[2 * q3][0]     = xv[2 * q3][0] + lo2f(u.x);
            y1tm[2 * q3][1]     = xv[2 * q3][1] + hi2f(u.x);
            y1tm[2 * q3][2]     = xv[2 * q3][2] + lo2f(u.y);
            y1tm[2 * q3][3]     = xv[2 * q3][3] + hi2f(u.y);
            y1tm[2 * q3 + 1][0] = xv[2 * q3 + 1][0] + lo2f(u.z);
            y1tm[2 * q3 + 1][1] = xv[2 * q3 + 1][1] + hi2f(u.z);
            y1tm[2 * q3 + 1][2] = xv[2 * q3 + 1][2] + lo2f(u.w);
            y1tm[2 * q3 + 1][3] = xv[2 * q3 + 1][3] + hi2f(u.w);
        }
        float s1 = 0.f, s2 = 0.f;
#pragma unroll
        for (int q = 0; q < 6; ++q)
#pragma unroll
            for (int r = 0; r < 4; ++r) { s1 += y1tm[q][r]; s2 = fmaf(y1tm[q][r], y1tm[q][r], s2); }
        s1 += __shfl_xor(s1, 1);  s2 += __shfl_xor(s2, 1);
        s1 += __shfl_xor(s1, 2);  s2 += __shfl_xor(s2, 2);
        const float mean = s1 * (1.f / CCH);
        const float rstd = rsqrtf(s2 * (1.f / CCH) - mean * mean + 1e-5f);
        unsigned o[12];
#pragma unroll
        for (int q = 0; q < 6; ++q) {
            const f32x4 wv = *(const f32x4*)&n2w[sub * 24 + 4 * q];
            const f32x4 bv = *(const f32x4*)&n2b[sub * 24 + 4 * q];
            float a0 = (y1tm[q][0] - mean) * rstd * wv[0] + bv[0];
            float a1 = (y1tm[q][1] - mean) * rstd * wv[1] + bv[1];
            float a2 = (y1tm[q][2] - mean) * rstd * wv[2] + bv[2];
            float a3 = (y1tm[q][3] - mean) * rstd * wv[3] + bv[3];
            o[2 * q] = cvtpk(a0, a1); o[2 * q + 1] = cvtpk(a2, a3);
        }
        unsigned* dst = (unsigned*)&sR1[tm * XW_LD + sub * 24];
#pragma unroll
        for (int q = 0; q < 3; ++q) {
            uint4 u; u.x = o[4 * q]; u.y = o[4 * q + 1]; u.z = o[4 * q + 2]; u.w = o[4 * q + 3];
            *(uint4*)(dst + 4 * q) = u;
        }
    }
    __syncthreads();   // B5: XN complete (all rows)

    // ---- Phase 6: MLP N-split, H in halves, persistent acc2[cti][mt].
    // XN frags re-read from sR1 per (nt,ks): XN stays valid until the final
    // mlp-out write, which happens after the last "H complete" barrier. ----
    f32x4 acc2[2][4];
#pragma unroll
    for (int ci = 0; ci < 2; ++ci)
#pragma unroll
        for (int mt = 0; mt < 4; ++mt) acc2[ci][mt] = (f32x4){0, 0, 0, 0};
    const unsigned short* w2p = wsq + W2_OFF;
#pragma unroll 1
    for (int half = 0; half < 2; ++half) {
        const unsigned short* w1p = wsq + W1_OFF + (size_t)half * 12 * 3 * 64 * 8;
        for (int nt = wave; nt < 12; nt += 4) {
            f32x4 acc[4] = {{0,0,0,0},{0,0,0,0},{0,0,0,0},{0,0,0,0}};
#pragma unroll
            for (int ks = 0; ks < 3; ++ks) {
                const bf16x8 wf = *(const bf16x8*)(w1p + ((size_t)(nt * 3 + ks) * 64 + lane) * 8);
#pragma unroll
                for (int mt = 0; mt < 4; ++mt) {
                    const bf16x8 xf = *(const bf16x8*)&sR1[(mt * 16 + l15) * XW_LD + ks * 32 + l16 * 8];
                    acc[mt] = __builtin_amdgcn_mfma_f32_16x16x32_bf16(wf, xf, acc[mt], 0, 0, 0);
                }
            }
            const f32x4 b1v = *(const f32x4*)&b1[(half * 12 + nt) * 16 + 4 * l16];
#pragma unroll
            for (int mt = 0; mt < 4; ++mt) {
                uint2 u;
                u.x = cvtpk(gelu_t(acc[mt][0] + b1v[0]), gelu_t(acc[mt][1] + b1v[1]));
                u.y = cvtpk(gelu_t(acc[mt][2] + b1v[2]), gelu_t(acc[mt][3] + b1v[3]));
                *(uint2*)&sQK[(mt * 16 + l15) * H_LD + nt * 16 + 4 * l16] = u;
            }
        }
        __syncthreads();   // H(half) complete
#pragma unroll
        for (int k6 = 0; k6 < 6; ++k6) {
            bf16x8 hfr[4];
#pragma unroll
            for (int mt = 0; mt < 4; ++mt)
                hfr[mt] = *(const bf16x8*)&sQK[(mt * 16 + l15) * H_LD + k6 * 32 + l16 * 8];
#pragma unroll
            for (int ci = 0; ci < 2; ++ci) {
                const int ct = wave + 4 * ci;
                if (ct < 6) {
                    const bf16x8 wf = *(const bf16x8*)(w2p + ((size_t)(ct * 12 + half * 6 + k6) * 64 + lane) * 8);
#pragma unroll
                    for (int mt = 0; mt < 4; ++mt)
                        acc2[ci][mt] = __builtin_amdgcn_mfma_f32_16x16x32_bf16(wf, hfr[mt], acc2[ci][mt], 0, 0, 0);
                }
            }
        }
        if (half == 0) __syncthreads();   // H consumed before overwrite
    }

    // ---- Final: mlp-out chan-major (all rows) -> B8 -> token-major +y1, coalesced store ----
    {
#pragma unroll
        for (int ci = 0; ci < 2; ++ci) {
            const int ct = wave + 4 * ci;
            if (ct < 6) {
                const f32x4 b2v = *(const f32x4*)&b2[ct * 16 + 4 * l16];
#pragma unroll
                for (int mt = 0; mt < 4; ++mt) {
                    uint2 u;
                    u.x = cvtpk(acc2[ci][mt][0] + b2v[0], acc2[ci][mt][1] + b2v[1]);
                    u.y = cvtpk(acc2[ci][mt][2] + b2v[2], acc2[ci][mt][3] + b2v[3]);
                    *(uint2*)&sR1[(mt * 16 + l15) * XW_LD + ct * 16 + 4 * l16] = u;
                }
            }
        }
    }
    __syncthreads();   // B8: mlp-out complete
    {
        const unsigned* src = (const unsigned*)&sR1[tm * XW_LD + sub * 24];
        float* yr = y + rowtm + sub * 24;
#pragma unroll
        for (int q3 = 0; q3 < 3; ++q3) {
            const uint4 u = *(const uint4*)(src + 4 * q3);
            f32x4 o0, o1;
            o0[0] = y1tm[2 * q3][0] + lo2f(u.x);
            o0[1] = y1tm[2 * q3][1] + hi2f(u.x);
            o0[2] = y1tm[2 * q3][2] + lo2f(u.y);
            o0[3] = y1tm[2 * q3][3] + hi2f(u.y);
            o1[0] = y1tm[2 * q3 + 1][0] + lo2f(u.z);
            o1[1] = y1tm[2 * q3 + 1][1] + hi2f(u.z);
            o1[2] = y1tm[2 * q3 + 1][2] + lo2f(u.w);
            o1[3] = y1tm[2 * q3 + 1][3] + hi2f(u.w);
            *(f32x4*)(yr + 8 * q3)     = o0;
            *(f32x4*)(yr + 8 * q3 + 4) = o1;
        }
    }
}

extern "C" void kernel_launch(void* const* d_in, const int* in_sizes, int n_in,
                              void* d_out, int out_size, void* d_ws, size_t ws_size,
                              hipStream_t stream)
{
    const float* x    = (const float*)d_in[0];
    const float* n1w  = (const float*)d_in[1];
    const float* n1b  = (const float*)d_in[2];
    const float* qkvw = (const float*)d_in[3];
    const float* qkvb = (const float*)d_in[4];
    const float* rpb  = (const float*)d_in[5];
    const float* pw   = (const float*)d_in[6];
    const float* pb   = (const float*)d_in[7];
    const float* n2w  = (const float*)d_in[8];
    const float* n2b  = (const float*)d_in[9];
    const float* w1   = (const float*)d_in[10];
    const float* b1   = (const float*)d_in[11];
    const float* w2   = (const float*)d_in[12];
    const float* b2   = (const float*)d_in[13];
    float* out = (float*)d_out;

    unsigned short* wsq = (unsigned short*)d_ws;   // 319488 B used

    prep<<<dim3(624), dim3(256), 0, stream>>>(qkvw, pw, w1, w2, rpb, wsq);
    fused<<<dim3(8192), dim3(256), 0, stream>>>(x, n1w, n1b, qkvb, pb, n2w, n2b,
                                                b1, b2, wsq, out);
}